// Round 3
// baseline (879.916 us; speedup 1.0000x reference)
//
#include <hip/hip_runtime.h>

#define NE 640000
#define NN 20000

typedef __attribute__((ext_vector_type(8))) short s16x8;
typedef __attribute__((ext_vector_type(4))) short s16x4;
typedef __attribute__((ext_vector_type(4))) float f32x4;

__device__ __forceinline__ short f2bf(float f) {
  unsigned int u = __float_as_uint(f);
  u += 0x7fffu + ((u >> 16) & 1u);   // RNE
  return (short)(u >> 16);
}

__device__ __forceinline__ s16x8 cvt8(f32x4 a, f32x4 b) {
  s16x8 o;
  o[0]=f2bf(a[0]); o[1]=f2bf(a[1]); o[2]=f2bf(a[2]); o[3]=f2bf(a[3]);
  o[4]=f2bf(b[0]); o[5]=f2bf(b[1]); o[6]=f2bf(b[2]); o[7]=f2bf(b[3]);
  return o;
}

// Stage W1[192][128] -> sW1t[h][k^swz(h)] (transposed bf16, XOR-swizzled so
// the in-loop b128 fragment reads across 16 h-rows spread over banks);
// W2[128][64] -> sW2t likewise. 1024 threads.
__device__ __forceinline__ void stage_weights(const float* W1, const float* W2,
                                              const float* b1, const float* b2,
                                              short* sW1t, short* sW2t,
                                              float* sB1, float* sB2, int t) {
  #pragma unroll
  for (int i = 0; i < 6; ++i) {
    int idx4 = t + i * 1024;                // 6144 float4
    int k = idx4 >> 5;                      // k-dim 0..191
    int h0 = (idx4 & 31) << 2;              // h-dim
    f32x4 v = ((const f32x4*)W1)[idx4];
    #pragma unroll
    for (int j = 0; j < 4; ++j) {
      int h = h0 + j;
      sW1t[h * 192 + (k ^ ((h & 7) << 3))] = f2bf(v[j]);
    }
  }
  #pragma unroll
  for (int i = 0; i < 2; ++i) {
    int idx4 = t + i * 1024;                // 2048 float4
    int k = idx4 >> 4;                      // k-dim 0..127
    int h0 = (idx4 & 15) << 2;
    f32x4 v = ((const f32x4*)W2)[idx4];
    #pragma unroll
    for (int j = 0; j < 4; ++j) {
      int h = h0 + j;
      sW2t[h * 128 + (k ^ ((h & 7) << 3))] = f2bf(v[j]);
    }
  }
  if (t < 128) sB1[t] = b1[t];
  else if (t < 192) sB2[t - 128] = b2[t - 128];
}

// One wave processes 16 rows: out = relu([p0|p1|p2] @ W1 + b1) @ W2 + b2.
// Swapped-operand MFMA (A = W^T from LDS per-use, B = input rows direct from
// global). Lane (r,g): B-frag = row r, features (kk&1)*32+g*8; D: col=edge r,
// rows = h g*4+q. Eh round-trips through wave-private LDS (XOR-swizzled).
__device__ __forceinline__ void mlp16(const float* p0, const float* p1, const float* p2,
                                      const short* sW1t, const short* sW2t,
                                      const float* sB1, const float* sB2,
                                      short* ehRow, int swz, int r, int g,
                                      float* out) {
  const int c = g * 8;
  f32x4 L[12];
  L[0]  = *(const f32x4*)(p0 + c);      L[1]  = *(const f32x4*)(p0 + c + 4);
  L[2]  = *(const f32x4*)(p0 + 32 + c); L[3]  = *(const f32x4*)(p0 + 36 + c);
  L[4]  = *(const f32x4*)(p1 + c);      L[5]  = *(const f32x4*)(p1 + c + 4);
  L[6]  = *(const f32x4*)(p1 + 32 + c); L[7]  = *(const f32x4*)(p1 + 36 + c);
  L[8]  = *(const f32x4*)(p2 + c);      L[9]  = *(const f32x4*)(p2 + c + 4);
  L[10] = *(const f32x4*)(p2 + 32 + c); L[11] = *(const f32x4*)(p2 + 36 + c);
  s16x8 ef[6];
  #pragma unroll
  for (int kk = 0; kk < 6; ++kk) ef[kk] = cvt8(L[2*kk], L[2*kk+1]);

  const f32x4 zero = {0.f, 0.f, 0.f, 0.f};
  f32x4 acc1[8];
  #pragma unroll
  for (int n = 0; n < 8; ++n) acc1[n] = zero;
  #pragma unroll
  for (int kk = 0; kk < 6; ++kk) {
    const int ko = (kk * 32 + g * 8) ^ swz;
    #pragma unroll
    for (int n = 0; n < 8; ++n) {
      s16x8 wf = *(const s16x8*)&sW1t[(n * 16 + r) * 192 + ko];
      acc1[n] = __builtin_amdgcn_mfma_f32_16x16x32_bf16(wf, ef[kk], acc1[n], 0, 0, 0);
    }
  }
  // bias + relu + packed bf16 write into this lane's edge row of Eh
  #pragma unroll
  for (int n = 0; n < 8; ++n) {
    f32x4 b = *(const f32x4*)(sB1 + n * 16 + g * 4);
    s16x4 pk;
    #pragma unroll
    for (int q = 0; q < 4; ++q) {
      float v = acc1[n][q] + b[q];
      pk[q] = f2bf(v > 0.f ? v : 0.f);
    }
    *(s16x4*)&ehRow[(n * 16 + g * 4) ^ swz] = pk;
  }
  // layer 2 (within-wave LDS ordering: DS pipe is in-order per wave)
  f32x4 acc2[4];
  #pragma unroll
  for (int n = 0; n < 4; ++n) acc2[n] = zero;
  #pragma unroll
  for (int kk = 0; kk < 4; ++kk) {
    const int ko = (kk * 32 + g * 8) ^ swz;
    s16x8 hf = *(const s16x8*)&ehRow[ko];
    #pragma unroll
    for (int n = 0; n < 4; ++n) {
      s16x8 wf = *(const s16x8*)&sW2t[(n * 16 + r) * 128 + ko];
      acc2[n] = __builtin_amdgcn_mfma_f32_16x16x32_bf16(wf, hf, acc2[n], 0, 0, 0);
    }
  }
  #pragma unroll
  for (int n = 0; n < 4; ++n) {
    f32x4 b = *(const f32x4*)(sB2 + n * 16 + g * 4);
    f32x4 v = acc2[n] + b;
    *(f32x4*)(out + n * 16 + g * 4) = v;
  }
}

// ---------------- CSR build ----------------

__global__ void count_kernel(const int* __restrict__ eidx, int* __restrict__ cursor) {
  for (int e = blockIdx.x * blockDim.x + threadIdx.x; e < NE;
       e += gridDim.x * blockDim.x)
    atomicAdd(&cursor[eidx[NE + e]], 1);
}

__global__ __launch_bounds__(1024)
void scan_kernel(int* __restrict__ cursor, int* __restrict__ offs) {
  __shared__ int part[1024];
  const int t = threadIdx.x;
  const int CH = 20;                         // 1024*20 >= NN
  const int lo = t * CH, hi = min(lo + CH, NN);
  int s = 0;
  for (int i = lo; i < hi; ++i) s += cursor[i];
  part[t] = s;
  __syncthreads();
  for (int d = 1; d < 1024; d <<= 1) {
    int u = (t >= d) ? part[t - d] : 0;
    __syncthreads();
    part[t] += u;
    __syncthreads();
  }
  int run = part[t] - s;                     // exclusive base
  for (int i = lo; i < hi; ++i) {
    int c = cursor[i];
    offs[i] = run;
    cursor[i] = run;
    run += c;
  }
  if (t == 1023) offs[NN] = NE;
}

__global__ void scatter_kernel(const int* __restrict__ eidx,
                               int* __restrict__ cursor, int* __restrict__ elist) {
  for (int e = blockIdx.x * blockDim.x + threadIdx.x; e < NE;
       e += gridDim.x * blockDim.x) {
    int pos = atomicAdd(&cursor[eidx[NE + e]], 1);
    elist[pos] = e;
  }
}

// ---------------- edge model ----------------
__global__ __launch_bounds__(1024, 4)
void edge_kernel(const float* __restrict__ x, const int* __restrict__ eidx,
                 const float* __restrict__ ea,
                 const float* __restrict__ We1, const float* __restrict__ be1,
                 const float* __restrict__ We2, const float* __restrict__ be2,
                 float* __restrict__ edge_out)
{
  __shared__ short sW1t[128 * 192];
  __shared__ short sW2t[64 * 128];
  __shared__ short sEh[16 * 16 * 128];
  __shared__ float sB1[128];
  __shared__ float sB2[64];

  const int t = threadIdx.x;
  stage_weights(We1, We2, be1, be2, sW1t, sW2t, sB1, sB2, t);
  __syncthreads();

  const int wv = t >> 6;
  const int lane = t & 63;
  const int r = lane & 15;
  const int g = lane >> 4;
  const int swz = (r & 7) << 3;
  short* ehRow = &sEh[(wv * 16 + r) * 128];

  const int NT = NE / 16;                    // 40000 wave-tasks
  for (int task = blockIdx.x * 16 + wv; task < NT; task += (int)gridDim.x * 16) {
    const int e0 = task * 16 + r;
    const int s = eidx[e0];
    const int d = eidx[NE + e0];
    mlp16(x + (size_t)s * 64, x + (size_t)d * 64, ea + (size_t)e0 * 64,
          sW1t, sW2t, sB1, sB2, ehRow, swz, r, g,
          edge_out + (size_t)e0 * 64);
  }
}

// ---------------- aggregation (gather) ----------------
__global__ __launch_bounds__(256)
void agg_kernel(const float* __restrict__ eo, const int* __restrict__ offs,
                const int* __restrict__ elist, float* __restrict__ agg) {
  const int w = threadIdx.x >> 6;
  const int lane = threadIdx.x & 63;
  for (int i = blockIdx.x * 4 + w; i < NN; i += (int)gridDim.x * 4) {
    int j = offs[i];
    const int end = offs[i + 1];
    float acc = 0.f;
    for (; j + 4 <= end; j += 4) {
      int e0 = elist[j], e1 = elist[j+1], e2 = elist[j+2], e3 = elist[j+3];
      float v0 = eo[(size_t)e0*64 + lane];
      float v1 = eo[(size_t)e1*64 + lane];
      float v2 = eo[(size_t)e2*64 + lane];
      float v3 = eo[(size_t)e3*64 + lane];
      acc += (v0 + v1) + (v2 + v3);
    }
    for (; j < end; ++j) acc += eo[(size_t)elist[j]*64 + lane];
    agg[(size_t)i*64 + lane] = acc;
  }
}

// ---------------- node model ----------------
// agg aliases x_out: wave reads rows task*16..+15 then overwrites exactly those.
__global__ __launch_bounds__(1024, 4)
void node_kernel(const float* __restrict__ x, const float* agg,
                 const float* __restrict__ f,
                 const float* __restrict__ Wn1, const float* __restrict__ bn1,
                 const float* __restrict__ Wn2, const float* __restrict__ bn2,
                 float* x_out)
{
  __shared__ short sW1t[128 * 192];
  __shared__ short sW2t[64 * 128];
  __shared__ short sEh[16 * 16 * 128];
  __shared__ float sB1[128];
  __shared__ float sB2[64];

  const int t = threadIdx.x;
  stage_weights(Wn1, Wn2, bn1, bn2, sW1t, sW2t, sB1, sB2, t);
  __syncthreads();

  const int wv = t >> 6;
  const int lane = t & 63;
  const int r = lane & 15;
  const int g = lane >> 4;
  const int swz = (r & 7) << 3;
  short* ehRow = &sEh[(wv * 16 + r) * 128];

  const int NT = NN / 16;                    // 1250 wave-tasks
  for (int task = blockIdx.x * 16 + wv; task < NT; task += (int)gridDim.x * 16) {
    const int i0 = task * 16 + r;
    mlp16(x + (size_t)i0 * 64, agg + (size_t)i0 * 64, f + (size_t)i0 * 64,
          sW1t, sW2t, sB1, sB2, ehRow, swz, r, g,
          x_out + (size_t)i0 * 64);
  }
}

extern "C" void kernel_launch(void* const* d_in, const int* in_sizes, int n_in,
                              void* d_out, int out_size, void* d_ws, size_t ws_size,
                              hipStream_t stream) {
  const float* x   = (const float*)d_in[0];
  const int*   ei  = (const int*)d_in[1];
  const float* ea  = (const float*)d_in[2];
  const float* f   = (const float*)d_in[3];
  const float* We1 = (const float*)d_in[4];
  const float* be1 = (const float*)d_in[5];
  const float* We2 = (const float*)d_in[6];
  const float* be2 = (const float*)d_in[7];
  const float* Wn1 = (const float*)d_in[8];
  const float* bn1 = (const float*)d_in[9];
  const float* Wn2 = (const float*)d_in[10];
  const float* bn2 = (const float*)d_in[11];

  float* x_out    = (float*)d_out;                    // [20000*64] — doubles as agg
  float* edge_out = x_out + (size_t)NN * 64;          // [640000*64]

  // CSR scratch in d_ws: cursor[NN] | offs[NN+1] | elist[NE]  (~2.8 MB)
  int* cursor = (int*)d_ws;
  int* offs   = cursor + NN;
  int* elist  = offs + NN + 8;

  hipMemsetAsync(cursor, 0, NN * sizeof(int), stream);
  count_kernel<<<512, 256, 0, stream>>>(ei, cursor);
  scan_kernel<<<1, 1024, 0, stream>>>(cursor, offs);
  scatter_kernel<<<512, 256, 0, stream>>>(ei, cursor, elist);
  edge_kernel<<<256, 1024, 0, stream>>>(x, ei, ea, We1, be1, We2, be2, edge_out);
  agg_kernel<<<1024, 256, 0, stream>>>(edge_out, offs, elist, x_out);
  node_kernel<<<79, 1024, 0, stream>>>(x, x_out, f, Wn1, bn1, Wn2, bn2, x_out);
}

// Round 4
// 715.752 us; speedup vs baseline: 1.2294x; 1.2294x over previous
//
#include <hip/hip_runtime.h>

#define NE 640000
#define NN 20000
#define NT_E (NE / 16)   // 40000 wave-tasks, 16 rows each
#define NT_N (NN / 16)   // 1250

typedef __attribute__((ext_vector_type(8))) short s16x8;
typedef __attribute__((ext_vector_type(4))) short s16x4;
typedef __attribute__((ext_vector_type(4))) float f32x4;

__device__ __forceinline__ short f2bf(float f) {
  unsigned int u = __float_as_uint(f);
  u += 0x7fffu + ((u >> 16) & 1u);   // RNE
  return (short)(u >> 16);
}

__device__ __forceinline__ s16x8 cvt8(f32x4 a, f32x4 b) {
  s16x8 o;
  o[0]=f2bf(a[0]); o[1]=f2bf(a[1]); o[2]=f2bf(a[2]); o[3]=f2bf(a[3]);
  o[4]=f2bf(b[0]); o[5]=f2bf(b[1]); o[6]=f2bf(b[2]); o[7]=f2bf(b[3]);
  return o;
}

// Stage W1[192][128] -> sW1t[h][k ^ swz(h)] (transposed bf16, XOR-swizzled);
// W2[128][64] -> sW2t likewise. 512 threads.
__device__ __forceinline__ void stage_weights(const float* W1, const float* W2,
                                              const float* b1, const float* b2,
                                              short* sW1t, short* sW2t,
                                              float* sB1, float* sB2, int t) {
  #pragma unroll
  for (int i = 0; i < 12; ++i) {
    int idx4 = t + i * 512;                 // 6144 float4
    int k = idx4 >> 5;                      // k-dim 0..191
    int h0 = (idx4 & 31) << 2;              // h-dim
    f32x4 v = ((const f32x4*)W1)[idx4];
    #pragma unroll
    for (int j = 0; j < 4; ++j) {
      int h = h0 + j;
      sW1t[h * 192 + (k ^ ((h & 7) << 3))] = f2bf(v[j]);
    }
  }
  #pragma unroll
  for (int i = 0; i < 4; ++i) {
    int idx4 = t + i * 512;                 // 2048 float4
    int k = idx4 >> 4;                      // k-dim 0..127
    int h0 = (idx4 & 15) << 2;
    f32x4 v = ((const f32x4*)W2)[idx4];
    #pragma unroll
    for (int j = 0; j < 4; ++j) {
      int h = h0 + j;
      sW2t[h * 128 + (k ^ ((h & 7) << 3))] = f2bf(v[j]);
    }
  }
  if (t < 128) sB1[t] = b1[t];
  else if (t < 192) sB2[t - 128] = b2[t - 128];
}

// Load one row-triple's 12 f32x4 fragments for this lane (c = g*8 floats).
__device__ __forceinline__ void loadL(const float* p0, const float* p1,
                                      const float* p2, int c, f32x4* L) {
  L[0]  = *(const f32x4*)(p0 + c);      L[1]  = *(const f32x4*)(p0 + c + 4);
  L[2]  = *(const f32x4*)(p0 + 32 + c); L[3]  = *(const f32x4*)(p0 + 36 + c);
  L[4]  = *(const f32x4*)(p1 + c);      L[5]  = *(const f32x4*)(p1 + c + 4);
  L[6]  = *(const f32x4*)(p1 + 32 + c); L[7]  = *(const f32x4*)(p1 + 36 + c);
  L[8]  = *(const f32x4*)(p2 + c);      L[9]  = *(const f32x4*)(p2 + c + 4);
  L[10] = *(const f32x4*)(p2 + 32 + c); L[11] = *(const f32x4*)(p2 + 36 + c);
}

// out = relu([p0|p1|p2] @ W1 + b1) @ W2 + b2 for 16 rows per wave.
// Swapped-operand MFMA: A = W^T (LDS, per-use), B = input rows (registers).
// D-layout: col = row r, rows = h (g*4+q). Eh round-trips via wave-private
// swizzled LDS (within-wave DS ordering, no barrier).
__device__ __forceinline__ void mlp_compute(const f32x4* L,
                                            const short* sW1t, const short* sW2t,
                                            const float* sB1, const float* sB2,
                                            short* ehRow, int swz, int r, int g,
                                            float* out) {
  s16x8 ef[6];
  #pragma unroll
  for (int kk = 0; kk < 6; ++kk) ef[kk] = cvt8(L[2*kk], L[2*kk+1]);

  const f32x4 zero = {0.f, 0.f, 0.f, 0.f};
  f32x4 acc1[8];
  #pragma unroll
  for (int n = 0; n < 8; ++n) acc1[n] = zero;
  #pragma unroll
  for (int kk = 0; kk < 6; ++kk) {
    const int ko = (kk * 32 + g * 8) ^ swz;
    #pragma unroll
    for (int n = 0; n < 8; ++n) {
      s16x8 wf = *(const s16x8*)&sW1t[(n * 16 + r) * 192 + ko];
      acc1[n] = __builtin_amdgcn_mfma_f32_16x16x32_bf16(wf, ef[kk], acc1[n], 0, 0, 0);
    }
  }
  #pragma unroll
  for (int n = 0; n < 8; ++n) {
    f32x4 b = *(const f32x4*)(sB1 + n * 16 + g * 4);
    s16x4 pk;
    #pragma unroll
    for (int q = 0; q < 4; ++q) {
      float v = acc1[n][q] + b[q];
      pk[q] = f2bf(v > 0.f ? v : 0.f);
    }
    *(s16x4*)&ehRow[(n * 16 + g * 4) ^ swz] = pk;
  }
  f32x4 acc2[4];
  #pragma unroll
  for (int n = 0; n < 4; ++n) acc2[n] = zero;
  #pragma unroll
  for (int kk = 0; kk < 4; ++kk) {
    const int ko = (kk * 32 + g * 8) ^ swz;
    s16x8 hf = *(const s16x8*)&ehRow[ko];
    #pragma unroll
    for (int n = 0; n < 4; ++n) {
      s16x8 wf = *(const s16x8*)&sW2t[(n * 16 + r) * 128 + ko];
      acc2[n] = __builtin_amdgcn_mfma_f32_16x16x32_bf16(wf, hf, acc2[n], 0, 0, 0);
    }
  }
  #pragma unroll
  for (int n = 0; n < 4; ++n) {
    f32x4 b = *(const f32x4*)(sB2 + n * 16 + g * 4);
    f32x4 v = acc2[n] + b;
    *(f32x4*)(out + n * 16 + g * 4) = v;
  }
}

// ---------------- CSR build ----------------

__global__ void count_kernel(const int* __restrict__ eidx, int* __restrict__ cursor) {
  for (int e = blockIdx.x * blockDim.x + threadIdx.x; e < NE;
       e += gridDim.x * blockDim.x)
    atomicAdd(&cursor[eidx[NE + e]], 1);
}

__global__ __launch_bounds__(1024)
void scan_kernel(int* __restrict__ cursor, int* __restrict__ offs) {
  __shared__ int part[1024];
  const int t = threadIdx.x;
  const int CH = 20;                         // 1024*20 >= NN
  const int lo = t * CH, hi = min(lo + CH, NN);
  int s = 0;
  for (int i = lo; i < hi; ++i) s += cursor[i];
  part[t] = s;
  __syncthreads();
  for (int d = 1; d < 1024; d <<= 1) {
    int u = (t >= d) ? part[t - d] : 0;
    __syncthreads();
    part[t] += u;
    __syncthreads();
  }
  int run = part[t] - s;                     // exclusive base
  for (int i = lo; i < hi; ++i) {
    int c = cursor[i];
    offs[i] = run;
    cursor[i] = run;
    run += c;
  }
  if (t == 1023) offs[NN] = NE;
}

__global__ void scatter_kernel(const int* __restrict__ eidx,
                               int* __restrict__ cursor, int* __restrict__ elist) {
  for (int e = blockIdx.x * blockDim.x + threadIdx.x; e < NE;
       e += gridDim.x * blockDim.x) {
    int pos = atomicAdd(&cursor[eidx[NE + e]], 1);
    elist[pos] = e;
  }
}

// ---------------- edge model (2-deep pipelined) ----------------
__global__ __launch_bounds__(512, 2)
void edge_kernel(const float* __restrict__ x, const int* __restrict__ eidx,
                 const float* __restrict__ ea,
                 const float* __restrict__ We1, const float* __restrict__ be1,
                 const float* __restrict__ We2, const float* __restrict__ be2,
                 float* __restrict__ edge_out)
{
  __shared__ short sW1t[128 * 192];
  __shared__ short sW2t[64 * 128];
  __shared__ short sEh[8 * 16 * 128];
  __shared__ float sB1[128];
  __shared__ float sB2[64];

  const int t = threadIdx.x;
  stage_weights(We1, We2, be1, be2, sW1t, sW2t, sB1, sB2, t);
  __syncthreads();

  const int wv = t >> 6;                     // 0..7
  const int lane = t & 63;
  const int r = lane & 15;
  const int g = lane >> 4;
  const int c = g * 8;
  const int swz = (r & 7) << 3;
  short* ehRow = &sEh[(wv * 16 + r) * 128];

  const int task0 = blockIdx.x * 8 + wv;
  const int step = (int)gridDim.x * 8;

  f32x4 La[12], Lb[12];
  int ea0 = 0;
  if (task0 < NT_E) {
    const int e0 = task0 * 16 + r;
    ea0 = e0;
    const int s = eidx[e0], d = eidx[NE + e0];
    loadL(x + (size_t)s * 64, x + (size_t)d * 64, ea + (size_t)e0 * 64, c, La);
  }

  for (int tk = task0; tk < NT_E; tk += 2 * step) {
    const int t1 = tk + step;
    const bool vb = t1 < NT_E;
    int eb0 = 0;
    if (vb) {
      const int e0 = t1 * 16 + r;
      eb0 = e0;
      const int s = eidx[e0], d = eidx[NE + e0];
      loadL(x + (size_t)s * 64, x + (size_t)d * 64, ea + (size_t)e0 * 64, c, Lb);
    }
    mlp_compute(La, sW1t, sW2t, sB1, sB2, ehRow, swz, r, g,
                edge_out + (size_t)ea0 * 64);
    const int t2 = tk + 2 * step;
    if (t2 < NT_E) {
      const int e0 = t2 * 16 + r;
      ea0 = e0;
      const int s = eidx[e0], d = eidx[NE + e0];
      loadL(x + (size_t)s * 64, x + (size_t)d * 64, ea + (size_t)e0 * 64, c, La);
    }
    if (vb)
      mlp_compute(Lb, sW1t, sW2t, sB1, sB2, ehRow, swz, r, g,
                  edge_out + (size_t)eb0 * 64);
  }
}

// ---------------- aggregation (gather) ----------------
__global__ __launch_bounds__(256)
void agg_kernel(const float* __restrict__ eo, const int* __restrict__ offs,
                const int* __restrict__ elist, float* __restrict__ agg) {
  const int w = threadIdx.x >> 6;
  const int lane = threadIdx.x & 63;
  for (int i = blockIdx.x * 4 + w; i < NN; i += (int)gridDim.x * 4) {
    int j = offs[i];
    const int end = offs[i + 1];
    float acc0 = 0.f, acc1 = 0.f;
    for (; j + 8 <= end; j += 8) {
      int e0 = elist[j],   e1 = elist[j+1], e2 = elist[j+2], e3 = elist[j+3];
      int e4 = elist[j+4], e5 = elist[j+5], e6 = elist[j+6], e7 = elist[j+7];
      float v0 = eo[(size_t)e0*64 + lane];
      float v1 = eo[(size_t)e1*64 + lane];
      float v2 = eo[(size_t)e2*64 + lane];
      float v3 = eo[(size_t)e3*64 + lane];
      float v4 = eo[(size_t)e4*64 + lane];
      float v5 = eo[(size_t)e5*64 + lane];
      float v6 = eo[(size_t)e6*64 + lane];
      float v7 = eo[(size_t)e7*64 + lane];
      acc0 += (v0 + v1) + (v2 + v3);
      acc1 += (v4 + v5) + (v6 + v7);
    }
    for (; j < end; ++j) acc0 += eo[(size_t)elist[j]*64 + lane];
    agg[(size_t)i*64 + lane] = acc0 + acc1;
  }
}

// ---------------- node model ----------------
// agg aliases x_out: wave reads rows task*16..+15 then overwrites exactly those.
__global__ __launch_bounds__(512, 2)
void node_kernel(const float* __restrict__ x, const float* agg,
                 const float* __restrict__ f,
                 const float* __restrict__ Wn1, const float* __restrict__ bn1,
                 const float* __restrict__ Wn2, const float* __restrict__ bn2,
                 float* x_out)
{
  __shared__ short sW1t[128 * 192];
  __shared__ short sW2t[64 * 128];
  __shared__ short sEh[8 * 16 * 128];
  __shared__ float sB1[128];
  __shared__ float sB2[64];

  const int t = threadIdx.x;
  stage_weights(Wn1, Wn2, bn1, bn2, sW1t, sW2t, sB1, sB2, t);
  __syncthreads();

  const int wv = t >> 6;
  const int lane = t & 63;
  const int r = lane & 15;
  const int g = lane >> 4;
  const int c = g * 8;
  const int swz = (r & 7) << 3;
  short* ehRow = &sEh[(wv * 16 + r) * 128];

  for (int task = blockIdx.x * 8 + wv; task < NT_N; task += (int)gridDim.x * 8) {
    const int i0 = task * 16 + r;
    f32x4 L[12];
    loadL(x + (size_t)i0 * 64, agg + (size_t)i0 * 64, f + (size_t)i0 * 64, c, L);
    mlp_compute(L, sW1t, sW2t, sB1, sB2, ehRow, swz, r, g,
                x_out + (size_t)i0 * 64);
  }
}

extern "C" void kernel_launch(void* const* d_in, const int* in_sizes, int n_in,
                              void* d_out, int out_size, void* d_ws, size_t ws_size,
                              hipStream_t stream) {
  const float* x   = (const float*)d_in[0];
  const int*   ei  = (const int*)d_in[1];
  const float* ea  = (const float*)d_in[2];
  const float* f   = (const float*)d_in[3];
  const float* We1 = (const float*)d_in[4];
  const float* be1 = (const float*)d_in[5];
  const float* We2 = (const float*)d_in[6];
  const float* be2 = (const float*)d_in[7];
  const float* Wn1 = (const float*)d_in[8];
  const float* bn1 = (const float*)d_in[9];
  const float* Wn2 = (const float*)d_in[10];
  const float* bn2 = (const float*)d_in[11];

  float* x_out    = (float*)d_out;                    // [20000*64] — doubles as agg
  float* edge_out = x_out + (size_t)NN * 64;          // [640000*64]

  // CSR scratch in d_ws: cursor[NN] | offs[NN+1] | elist[NE]  (~2.8 MB)
  int* cursor = (int*)d_ws;
  int* offs   = cursor + NN;
  int* elist  = offs + NN + 8;

  hipMemsetAsync(cursor, 0, NN * sizeof(int), stream);
  count_kernel<<<1024, 256, 0, stream>>>(ei, cursor);
  scan_kernel<<<1, 1024, 0, stream>>>(cursor, offs);
  scatter_kernel<<<1024, 256, 0, stream>>>(ei, cursor, elist);
  edge_kernel<<<256, 512, 0, stream>>>(x, ei, ea, We1, be1, We2, be2, edge_out);
  agg_kernel<<<1024, 256, 0, stream>>>(edge_out, offs, elist, x_out);
  node_kernel<<<160, 512, 0, stream>>>(x, x_out, f, Wn1, bn1, Wn2, bn2, x_out);
}

// Round 6
// 306.188 us; speedup vs baseline: 2.8738x; 2.3376x over previous
//
#include <hip/hip_runtime.h>

#define NE 640000
#define NN 20000

#define SEI 200   // Ein stride (shorts): 192 + 16B pad -> uniform granule spread
#define SEH 136   // Eh stride: 128 + 8

typedef __attribute__((ext_vector_type(8))) short s16x8;
typedef __attribute__((ext_vector_type(4))) short s16x4;
typedef __attribute__((ext_vector_type(4))) float f32x4;

__device__ __forceinline__ short f2bf(float f) {
  unsigned int u = __float_as_uint(f);
  u += 0x7fffu + ((u >> 16) & 1u);   // RNE
  return (short)(u >> 16);
}

__device__ __forceinline__ s16x8 cvt8(f32x4 a, f32x4 b) {
  s16x8 o;
  o[0]=f2bf(a[0]); o[1]=f2bf(a[1]); o[2]=f2bf(a[2]); o[3]=f2bf(a[3]);
  o[4]=f2bf(b[0]); o[5]=f2bf(b[1]); o[6]=f2bf(b[2]); o[7]=f2bf(b[3]);
  return o;
}

// One-time: W1[192][128] -> sW1t[h][k] bf16 transposed (stride 192);
// W2[128][64] -> sW2t[d][k] (stride 128). 256 threads.
__device__ __forceinline__ void stage_weights(const float* W1, const float* W2,
                                              short* sW1t, short* sW2t, int t) {
  #pragma unroll
  for (int i = 0; i < 24; ++i) {
    int idx4 = t + i * 256;                 // 6144 float4
    int k = idx4 >> 5;                      // k 0..191
    int h0 = (idx4 & 31) << 2;              // h
    f32x4 v = ((const f32x4*)W1)[idx4];
    sW1t[(h0+0)*192 + k] = f2bf(v[0]);
    sW1t[(h0+1)*192 + k] = f2bf(v[1]);
    sW1t[(h0+2)*192 + k] = f2bf(v[2]);
    sW1t[(h0+3)*192 + k] = f2bf(v[3]);
  }
  #pragma unroll
  for (int i = 0; i < 8; ++i) {
    int idx4 = t + i * 256;                 // 2048 float4
    int k = idx4 >> 4;                      // k 0..127
    int h0 = (idx4 & 15) << 2;
    f32x4 v = ((const f32x4*)W2)[idx4];
    sW2t[(h0+0)*128 + k] = f2bf(v[0]);
    sW2t[(h0+1)*128 + k] = f2bf(v[1]);
    sW2t[(h0+2)*128 + k] = f2bf(v[2]);
    sW2t[(h0+3)*128 + k] = f2bf(v[3]);
  }
}

// ---------------- CSR build ----------------

__global__ void count_kernel(const int* __restrict__ eidx, int* __restrict__ cursor) {
  for (int e = blockIdx.x * blockDim.x + threadIdx.x; e < NE;
       e += gridDim.x * blockDim.x)
    atomicAdd(&cursor[eidx[NE + e]], 1);
}

__global__ __launch_bounds__(1024)
void scan_kernel(int* __restrict__ cursor, int* __restrict__ offs) {
  __shared__ int part[1024];
  const int t = threadIdx.x;
  const int CH = 20;                         // 1024*20 >= NN
  const int lo = t * CH, hi = min(lo + CH, NN);
  int s = 0;
  for (int i = lo; i < hi; ++i) s += cursor[i];
  part[t] = s;
  __syncthreads();
  for (int d = 1; d < 1024; d <<= 1) {
    int u = (t >= d) ? part[t - d] : 0;
    __syncthreads();
    part[t] += u;
    __syncthreads();
  }
  int run = part[t] - s;                     // exclusive base
  for (int i = lo; i < hi; ++i) {
    int c = cursor[i];
    offs[i] = run;
    cursor[i] = run;
    run += c;
  }
  if (t == 1023) offs[NN] = NE;
}

__global__ void scatter_kernel(const int* __restrict__ eidx,
                               int* __restrict__ cursor, int* __restrict__ elist) {
  for (int e = blockIdx.x * blockDim.x + threadIdx.x; e < NE;
       e += gridDim.x * blockDim.x) {
    int pos = atomicAdd(&cursor[eidx[NE + e]], 1);
    elist[pos] = e;
  }
}

// ---------------- edge model ----------------
// 64-edge tile per block (4 waves cooperate). Wave w owns h-tiles {2w,2w+1}
// of layer 1 (weights in 48 VGPR) and d-tile w of layer 2 (16 VGPR).
// LDS phase map (bytes, smem = 65536):
//   staging: sW1t [0, 49152) | sW2t [49152, 65536)       -- exact fit
//   compute: sEin [0, 25600) | sEh  [25600, 43008)       -- fits (r5 bug: 51200+17408>64K)
__global__ __launch_bounds__(256, 2)
void edge_kernel(const float* __restrict__ x, const int* __restrict__ eidx,
                 const float* __restrict__ ea,
                 const float* __restrict__ We1, const float* __restrict__ be1,
                 const float* __restrict__ We2, const float* __restrict__ be2,
                 float* __restrict__ edge_out)
{
  __shared__ __align__(16) char smem[65536];
  short* sW1t = (short*)smem;                // [128*192] staging phase
  short* sW2t = (short*)(smem + 49152);      // [64*128]
  short* sEin = (short*)smem;                // [64][SEI]  compute phase
  short* sEh  = (short*)(smem + 25600);      // [64][SEH]

  const int t = threadIdx.x;
  stage_weights(We1, We2, sW1t, sW2t, t);
  __syncthreads();

  const int wv = t >> 6, lane = t & 63;
  const int r = lane & 15, g = lane >> 4;

  // weight fragments -> registers (A-operand rows = h / d dims)
  s16x8 w1f[2][6];
  #pragma unroll
  for (int nn = 0; nn < 2; ++nn)
    #pragma unroll
    for (int kk = 0; kk < 6; ++kk)
      w1f[nn][kk] = *(const s16x8*)&sW1t[((wv*2+nn)*16 + r)*192 + kk*32 + g*8];
  s16x8 w2f[4];
  #pragma unroll
  for (int kk = 0; kk < 4; ++kk)
    w2f[kk] = *(const s16x8*)&sW2t[(wv*16 + r)*128 + kk*32 + g*8];
  f32x4 b1r[2], b2r;
  #pragma unroll
  for (int nn = 0; nn < 2; ++nn)
    b1r[nn] = *(const f32x4*)(be1 + (wv*2+nn)*16 + g*4);
  b2r = *(const f32x4*)(be2 + wv*16 + g*4);
  __syncthreads();                           // frags read; LDS now free for Ein/Eh

  const int el = t >> 2, p = t & 3;          // edge slot / 16-col chunk
  short* stg = sEin + el*SEI + p*16;

  const f32x4 zero = {0.f, 0.f, 0.f, 0.f};
  const int nT = NE / 64;                    // 10000
  const int stride = (int)gridDim.x;

  s16x8 Lr[6];
  int tile = blockIdx.x;
  if (tile < nT) {                           // prologue: stage tile 0
    const int e = (tile << 6) + el;
    const int s = eidx[e], d = eidx[NE + e];
    const f32x4* ps = (const f32x4*)(x  + (size_t)s*64 + p*16);
    const f32x4* pd = (const f32x4*)(x  + (size_t)d*64 + p*16);
    const f32x4* pe = (const f32x4*)(ea + (size_t)e*64 + p*16);
    Lr[0]=cvt8(ps[0],ps[1]); Lr[1]=cvt8(ps[2],ps[3]);
    Lr[2]=cvt8(pd[0],pd[1]); Lr[3]=cvt8(pd[2],pd[3]);
    Lr[4]=cvt8(pe[0],pe[1]); Lr[5]=cvt8(pe[2],pe[3]);
    ((s16x8*)stg)[0]=Lr[0];       ((s16x8*)stg)[1]=Lr[1];
    ((s16x8*)(stg+64))[0]=Lr[2];  ((s16x8*)(stg+64))[1]=Lr[3];
    ((s16x8*)(stg+128))[0]=Lr[4]; ((s16x8*)(stg+128))[1]=Lr[5];
  }
  __syncthreads();

  while (tile < nT) {
    const int ebase = tile << 6;
    // ---- layer 1: acc1[nn][j] over 64 edges x 32 h ----
    f32x4 acc1[2][4];
    #pragma unroll
    for (int nn = 0; nn < 2; ++nn)
      #pragma unroll
      for (int j = 0; j < 4; ++j) acc1[nn][j] = zero;
    #pragma unroll
    for (int kk = 0; kk < 6; ++kk) {
      #pragma unroll
      for (int j = 0; j < 4; ++j) {
        s16x8 ef = *(const s16x8*)&sEin[(j*16 + r)*SEI + kk*32 + g*8];
        acc1[0][j] = __builtin_amdgcn_mfma_f32_16x16x32_bf16(w1f[0][kk], ef, acc1[0][j], 0, 0, 0);
        acc1[1][j] = __builtin_amdgcn_mfma_f32_16x16x32_bf16(w1f[1][kk], ef, acc1[1][j], 0, 0, 0);
      }
    }
    // bias + relu + bf16 pack -> Eh[edge][h]
    #pragma unroll
    for (int nn = 0; nn < 2; ++nn)
      #pragma unroll
      for (int j = 0; j < 4; ++j) {
        s16x4 pk;
        #pragma unroll
        for (int q = 0; q < 4; ++q) {
          float v = acc1[nn][j][q] + b1r[nn][q];
          pk[q] = f2bf(v > 0.f ? v : 0.f);
        }
        *(s16x4*)&sEh[(j*16 + r)*SEH + (wv*2+nn)*16 + g*4] = pk;
      }
    __syncthreads();                         // Eh ready; Ein free

    const int ntile = tile + stride;
    if (ntile < nT) {                        // prefetch next tile (loads hide under compute)
      const int e = (ntile << 6) + el;
      const int s = eidx[e], d = eidx[NE + e];
      const f32x4* ps = (const f32x4*)(x  + (size_t)s*64 + p*16);
      const f32x4* pd = (const f32x4*)(x  + (size_t)d*64 + p*16);
      const f32x4* pe = (const f32x4*)(ea + (size_t)e*64 + p*16);
      Lr[0]=cvt8(ps[0],ps[1]); Lr[1]=cvt8(ps[2],ps[3]);
      Lr[2]=cvt8(pd[0],pd[1]); Lr[3]=cvt8(pd[2],pd[3]);
      Lr[4]=cvt8(pe[0],pe[1]); Lr[5]=cvt8(pe[2],pe[3]);
    }
    // ---- layer 2: d-tile wv over 64 edges ----
    #pragma unroll
    for (int j = 0; j < 4; ++j) {
      f32x4 a2 = zero;
      #pragma unroll
      for (int kk = 0; kk < 4; ++kk) {
        s16x8 hf = *(const s16x8*)&sEh[(j*16 + r)*SEH + kk*32 + g*8];
        a2 = __builtin_amdgcn_mfma_f32_16x16x32_bf16(w2f[kk], hf, a2, 0, 0, 0);
      }
      f32x4 v = a2 + b2r;
      *(f32x4*)&edge_out[(size_t)(ebase + j*16 + r)*64 + wv*16 + g*4] = v;
    }
    if (ntile < nT) {                        // write staged regs -> Ein
      ((s16x8*)stg)[0]=Lr[0];       ((s16x8*)stg)[1]=Lr[1];
      ((s16x8*)(stg+64))[0]=Lr[2];  ((s16x8*)(stg+64))[1]=Lr[3];
      ((s16x8*)(stg+128))[0]=Lr[4]; ((s16x8*)(stg+128))[1]=Lr[5];
    }
    __syncthreads();                         // Ein(next) ready; Eh free
    tile = ntile;
  }
}

// ---------------- aggregation (gather) ----------------
__global__ __launch_bounds__(256)
void agg_kernel(const float* __restrict__ eo, const int* __restrict__ offs,
                const int* __restrict__ elist, float* __restrict__ agg) {
  const int w = threadIdx.x >> 6;
  const int lane = threadIdx.x & 63;
  for (int i = blockIdx.x * 4 + w; i < NN; i += (int)gridDim.x * 4) {
    int j = offs[i];
    const int end = offs[i + 1];
    float acc0 = 0.f, acc1 = 0.f;
    for (; j + 8 <= end; j += 8) {
      int e0 = elist[j],   e1 = elist[j+1], e2 = elist[j+2], e3 = elist[j+3];
      int e4 = elist[j+4], e5 = elist[j+5], e6 = elist[j+6], e7 = elist[j+7];
      float v0 = eo[(size_t)e0*64 + lane];
      float v1 = eo[(size_t)e1*64 + lane];
      float v2 = eo[(size_t)e2*64 + lane];
      float v3 = eo[(size_t)e3*64 + lane];
      float v4 = eo[(size_t)e4*64 + lane];
      float v5 = eo[(size_t)e5*64 + lane];
      float v6 = eo[(size_t)e6*64 + lane];
      float v7 = eo[(size_t)e7*64 + lane];
      acc0 += (v0 + v1) + (v2 + v3);
      acc1 += (v4 + v5) + (v6 + v7);
    }
    for (; j < end; ++j) acc0 += eo[(size_t)elist[j]*64 + lane];
    agg[(size_t)i*64 + lane] = acc0 + acc1;
  }
}

// ---------------- node model ----------------
// Same cooperative structure; agg aliases x_out (block reads rows of its tile,
// then overwrites exactly those rows; grid == nT so no cross-block hazard).
__global__ __launch_bounds__(256, 2)
void node_kernel(const float* __restrict__ x, const float* agg,
                 const float* __restrict__ f,
                 const float* __restrict__ Wn1, const float* __restrict__ bn1,
                 const float* __restrict__ Wn2, const float* __restrict__ bn2,
                 float* x_out)
{
  __shared__ __align__(16) char smem[65536];
  short* sW1t = (short*)smem;
  short* sW2t = (short*)(smem + 49152);
  short* sEin = (short*)smem;
  short* sEh  = (short*)(smem + 25600);

  const int t = threadIdx.x;
  stage_weights(Wn1, Wn2, sW1t, sW2t, t);
  __syncthreads();

  const int wv = t >> 6, lane = t & 63;
  const int r = lane & 15, g = lane >> 4;

  s16x8 w1f[2][6];
  #pragma unroll
  for (int nn = 0; nn < 2; ++nn)
    #pragma unroll
    for (int kk = 0; kk < 6; ++kk)
      w1f[nn][kk] = *(const s16x8*)&sW1t[((wv*2+nn)*16 + r)*192 + kk*32 + g*8];
  s16x8 w2f[4];
  #pragma unroll
  for (int kk = 0; kk < 4; ++kk)
    w2f[kk] = *(const s16x8*)&sW2t[(wv*16 + r)*128 + kk*32 + g*8];
  f32x4 b1r[2], b2r;
  #pragma unroll
  for (int nn = 0; nn < 2; ++nn)
    b1r[nn] = *(const f32x4*)(bn1 + (wv*2+nn)*16 + g*4);
  b2r = *(const f32x4*)(bn2 + wv*16 + g*4);
  __syncthreads();

  const int el = t >> 2, p = t & 3;
  short* stg = sEin + el*SEI + p*16;

  const f32x4 zero = {0.f, 0.f, 0.f, 0.f};
  const s16x8 z8 = {0,0,0,0,0,0,0,0};
  const int nT = (NN + 63) / 64;             // 313
  const int stride = (int)gridDim.x;

  s16x8 Lr[6];
  int tile = blockIdx.x;
  if (tile < nT) {
    const int i = (tile << 6) + el;
    if (i < NN) {
      const f32x4* ps = (const f32x4*)(x   + (size_t)i*64 + p*16);
      const f32x4* pa = (const f32x4*)(agg + (size_t)i*64 + p*16);
      const f32x4* pf = (const f32x4*)(f   + (size_t)i*64 + p*16);
      Lr[0]=cvt8(ps[0],ps[1]); Lr[1]=cvt8(ps[2],ps[3]);
      Lr[2]=cvt8(pa[0],pa[1]); Lr[3]=cvt8(pa[2],pa[3]);
      Lr[4]=cvt8(pf[0],pf[1]); Lr[5]=cvt8(pf[2],pf[3]);
    } else {
      Lr[0]=z8; Lr[1]=z8; Lr[2]=z8; Lr[3]=z8; Lr[4]=z8; Lr[5]=z8;
    }
    ((s16x8*)stg)[0]=Lr[0];       ((s16x8*)stg)[1]=Lr[1];
    ((s16x8*)(stg+64))[0]=Lr[2];  ((s16x8*)(stg+64))[1]=Lr[3];
    ((s16x8*)(stg+128))[0]=Lr[4]; ((s16x8*)(stg+128))[1]=Lr[5];
  }
  __syncthreads();

  while (tile < nT) {
    const int base = tile << 6;
    f32x4 acc1[2][4];
    #pragma unroll
    for (int nn = 0; nn < 2; ++nn)
      #pragma unroll
      for (int j = 0; j < 4; ++j) acc1[nn][j] = zero;
    #pragma unroll
    for (int kk = 0; kk < 6; ++kk) {
      #pragma unroll
      for (int j = 0; j < 4; ++j) {
        s16x8 ef = *(const s16x8*)&sEin[(j*16 + r)*SEI + kk*32 + g*8];
        acc1[0][j] = __builtin_amdgcn_mfma_f32_16x16x32_bf16(w1f[0][kk], ef, acc1[0][j], 0, 0, 0);
        acc1[1][j] = __builtin_amdgcn_mfma_f32_16x16x32_bf16(w1f[1][kk], ef, acc1[1][j], 0, 0, 0);
      }
    }
    #pragma unroll
    for (int nn = 0; nn < 2; ++nn)
      #pragma unroll
      for (int j = 0; j < 4; ++j) {
        s16x4 pk;
        #pragma unroll
        for (int q = 0; q < 4; ++q) {
          float v = acc1[nn][j][q] + b1r[nn][q];
          pk[q] = f2bf(v > 0.f ? v : 0.f);
        }
        *(s16x4*)&sEh[(j*16 + r)*SEH + (wv*2+nn)*16 + g*4] = pk;
      }
    __syncthreads();

    const int ntile = tile + stride;
    if (ntile < nT) {
      const int i = (ntile << 6) + el;
      if (i < NN) {
        const f32x4* ps = (const f32x4*)(x   + (size_t)i*64 + p*16);
        const f32x4* pa = (const f32x4*)(agg + (size_t)i*64 + p*16);
        const f32x4* pf = (const f32x4*)(f   + (size_t)i*64 + p*16);
        Lr[0]=cvt8(ps[0],ps[1]); Lr[1]=cvt8(ps[2],ps[3]);
        Lr[2]=cvt8(pa[0],pa[1]); Lr[3]=cvt8(pa[2],pa[3]);
        Lr[4]=cvt8(pf[0],pf[1]); Lr[5]=cvt8(pf[2],pf[3]);
      } else {
        Lr[0]=z8; Lr[1]=z8; Lr[2]=z8; Lr[3]=z8; Lr[4]=z8; Lr[5]=z8;
      }
    }
    #pragma unroll
    for (int j = 0; j < 4; ++j) {
      f32x4 a2 = zero;
      #pragma unroll
      for (int kk = 0; kk < 4; ++kk) {
        s16x8 hf = *(const s16x8*)&sEh[(j*16 + r)*SEH + kk*32 + g*8];
        a2 = __builtin_amdgcn_mfma_f32_16x16x32_bf16(w2f[kk], hf, a2, 0, 0, 0);
      }
      const int row = base + j*16 + r;
      if (row < NN) {
        f32x4 v = a2 + b2r;
        *(f32x4*)&x_out[(size_t)row*64 + wv*16 + g*4] = v;
      }
    }
    if (ntile < nT) {
      ((s16x8*)stg)[0]=Lr[0];       ((s16x8*)stg)[1]=Lr[1];
      ((s16x8*)(stg+64))[0]=Lr[2];  ((s16x8*)(stg+64))[1]=Lr[3];
      ((s16x8*)(stg+128))[0]=Lr[4]; ((s16x8*)(stg+128))[1]=Lr[5];
    }
    __syncthreads();
    tile = ntile;
  }
}

extern "C" void kernel_launch(void* const* d_in, const int* in_sizes, int n_in,
                              void* d_out, int out_size, void* d_ws, size_t ws_size,
                              hipStream_t stream) {
  const float* x   = (const float*)d_in[0];
  const int*   ei  = (const int*)d_in[1];
  const float* ea  = (const float*)d_in[2];
  const float* f   = (const float*)d_in[3];
  const float* We1 = (const float*)d_in[4];
  const float* be1 = (const float*)d_in[5];
  const float* We2 = (const float*)d_in[6];
  const float* be2 = (const float*)d_in[7];
  const float* Wn1 = (const float*)d_in[8];
  const float* bn1 = (const float*)d_in[9];
  const float* Wn2 = (const float*)d_in[10];
  const float* bn2 = (const float*)d_in[11];

  float* x_out    = (float*)d_out;                    // [20000*64] — doubles as agg
  float* edge_out = x_out + (size_t)NN * 64;          // [640000*64]

  // CSR scratch in d_ws: cursor[NN] | offs[NN+1] | elist[NE]  (~2.8 MB)
  int* cursor = (int*)d_ws;
  int* offs   = cursor + NN;
  int* elist  = offs + NN + 8;

  hipMemsetAsync(cursor, 0, NN * sizeof(int), stream);
  count_kernel<<<1024, 256, 0, stream>>>(ei, cursor);
  scan_kernel<<<1, 1024, 0, stream>>>(cursor, offs);
  scatter_kernel<<<1024, 256, 0, stream>>>(ei, cursor, elist);
  edge_kernel<<<512, 256, 0, stream>>>(x, ei, ea, We1, be1, We2, be2, edge_out);
  agg_kernel<<<1024, 256, 0, stream>>>(edge_out, offs, elist, x_out);
  node_kernel<<<313, 256, 0, stream>>>(x, x_out, f, Wn1, bn1, Wn2, bn2, x_out);
}

// Round 7
// 262.597 us; speedup vs baseline: 3.3508x; 1.1660x over previous
//
#include <hip/hip_runtime.h>

#define NE 640000
#define NN 20000
#define SEI 200   // Ein stride (shorts): 192 + pad
#define SEH 136   // Eh stride: 128 + pad

typedef __attribute__((ext_vector_type(8))) short s16x8;
typedef __attribute__((ext_vector_type(4))) short s16x4;
typedef __attribute__((ext_vector_type(4))) float f32x4;

__device__ __forceinline__ short f2bf(float f) {
  unsigned int u = __float_as_uint(f);
  u += 0x7fffu + ((u >> 16) & 1u);   // RNE
  return (short)(u >> 16);
}

__device__ __forceinline__ s16x8 cvt8(f32x4 a, f32x4 b) {
  s16x8 o;
  o[0]=f2bf(a[0]); o[1]=f2bf(a[1]); o[2]=f2bf(a[2]); o[3]=f2bf(a[3]);
  o[4]=f2bf(b[0]); o[5]=f2bf(b[1]); o[6]=f2bf(b[2]); o[7]=f2bf(b[3]);
  return o;
}

// Weight fragments straight from global (one-time; replaces LDS staging whose
// transposed scatter writes were a 32-way bank conflict, r6: 22.4M cycles).
// w1f[nn][kk][i] = W1[kk*32+g*8+i][(wv*2+nn)*16+r]; w2f likewise on W2.
__device__ __forceinline__ void load_wfrags(const float* W1, const float* W2,
                                            const float* b1, const float* b2,
                                            int wv, int r, int g,
                                            s16x8 w1f[2][6], s16x8 w2f[4],
                                            f32x4 b1r[2], f32x4* b2r) {
  #pragma unroll
  for (int nn = 0; nn < 2; ++nn) {
    const int h = (wv*2+nn)*16 + r;
    #pragma unroll
    for (int kk = 0; kk < 6; ++kk) {
      s16x8 wf;
      #pragma unroll
      for (int i = 0; i < 8; ++i)
        wf[i] = f2bf(W1[(size_t)(kk*32 + g*8 + i)*128 + h]);
      w1f[nn][kk] = wf;
    }
    b1r[nn] = *(const f32x4*)(b1 + (wv*2+nn)*16 + g*4);
  }
  const int h2 = wv*16 + r;
  #pragma unroll
  for (int kk = 0; kk < 4; ++kk) {
    s16x8 wf;
    #pragma unroll
    for (int i = 0; i < 8; ++i)
      wf[i] = f2bf(W2[(size_t)(kk*32 + g*8 + i)*64 + h2]);
    w2f[kk] = wf;
  }
  *b2r = *(const f32x4*)(b2 + wv*16 + g*4);
}

// ---------------- CSR build ----------------

__global__ void count_kernel(const int* __restrict__ eidx, int* __restrict__ cursor) {
  for (int e = blockIdx.x * blockDim.x + threadIdx.x; e < NE;
       e += gridDim.x * blockDim.x)
    atomicAdd(&cursor[eidx[NE + e]], 1);
}

__global__ __launch_bounds__(1024)
void scan_kernel(int* __restrict__ cursor, int* __restrict__ offs) {
  __shared__ int part[1024];
  const int t = threadIdx.x;
  const int CH = 20;                         // 1024*20 >= NN
  const int lo = t * CH, hi = min(lo + CH, NN);
  int s = 0;
  for (int i = lo; i < hi; ++i) s += cursor[i];
  part[t] = s;
  __syncthreads();
  for (int d = 1; d < 1024; d <<= 1) {
    int u = (t >= d) ? part[t - d] : 0;
    __syncthreads();
    part[t] += u;
    __syncthreads();
  }
  int run = part[t] - s;                     // exclusive base
  for (int i = lo; i < hi; ++i) {
    int c = cursor[i];
    offs[i] = run;
    cursor[i] = run;
    run += c;
  }
  if (t == 1023) offs[NN] = NE;
}

__global__ void scatter_kernel(const int* __restrict__ eidx,
                               int* __restrict__ cursor, int* __restrict__ elist) {
  for (int e = blockIdx.x * blockDim.x + threadIdx.x; e < NE;
       e += gridDim.x * blockDim.x) {
    int pos = atomicAdd(&cursor[eidx[NE + e]], 1);
    elist[pos] = e;
  }
}

// ---------------- edge model ----------------
// 64-edge tile per block, 4 waves cooperate (wave w: h-tiles {2w,2w+1} L1,
// d-tile w L2). Weights in registers from global. Double-buffered Ein with a
// 3-stage pipeline: write regs(t+1)->Ein, issue row loads(t+2), load idx(t+3)
// -> load-to-use distance = one full tile of compute.
#define LOAD_ROWS(sv, dv, ee) do {                                        \
    const f32x4* ps_ = (const f32x4*)(x  + (size_t)(sv)*64 + p*16);       \
    const f32x4* pd_ = (const f32x4*)(x  + (size_t)(dv)*64 + p*16);       \
    const f32x4* pe_ = (const f32x4*)(ea + (size_t)(ee)*64 + p*16);       \
    L[0]=ps_[0]; L[1]=ps_[1]; L[2]=ps_[2];  L[3]=ps_[3];                  \
    L[4]=pd_[0]; L[5]=pd_[1]; L[6]=pd_[2];  L[7]=pd_[3];                  \
    L[8]=pe_[0]; L[9]=pe_[1]; L[10]=pe_[2]; L[11]=pe_[3];                 \
  } while (0)

#define WRITE_EIN(buf) do {                                               \
    short* stg_ = (buf) + el*SEI + p*16;                                  \
    ((s16x8*)stg_)[0]       = cvt8(L[0], L[1]);                           \
    ((s16x8*)stg_)[1]       = cvt8(L[2], L[3]);                           \
    ((s16x8*)(stg_+64))[0]  = cvt8(L[4], L[5]);                           \
    ((s16x8*)(stg_+64))[1]  = cvt8(L[6], L[7]);                           \
    ((s16x8*)(stg_+128))[0] = cvt8(L[8], L[9]);                           \
    ((s16x8*)(stg_+128))[1] = cvt8(L[10], L[11]);                         \
  } while (0)

__global__ __launch_bounds__(256, 2)
void edge_kernel(const float* __restrict__ x, const int* __restrict__ eidx,
                 const float* __restrict__ ea,
                 const float* __restrict__ We1, const float* __restrict__ be1,
                 const float* __restrict__ We2, const float* __restrict__ be2,
                 float* __restrict__ edge_out)
{
  __shared__ __align__(16) short sEin[2][64 * SEI];   // 2 x 25600 B
  __shared__ __align__(16) short sEh[64 * SEH];       // 17408 B

  const int t = threadIdx.x;
  const int wv = t >> 6, lane = t & 63;
  const int r = lane & 15, g = lane >> 4;

  s16x8 w1f[2][6], w2f[4];
  f32x4 b1r[2], b2r;
  load_wfrags(We1, We2, be1, be2, wv, r, g, w1f, w2f, b1r, &b2r);

  const int el = t >> 2, p = t & 3;
  const int nT = NE / 64;                    // 10000
  const int S = (int)gridDim.x;
  const f32x4 zero = {0.f, 0.f, 0.f, 0.f};

  f32x4 L[12];
  int sN = 0, dN = 0;
  int tile = blockIdx.x;

  if (tile < nT) {                           // prologue
    int e = (tile << 6) + el;
    int sv = eidx[e], dv = eidx[NE + e];
    LOAD_ROWS(sv, dv, e);
    WRITE_EIN(sEin[0]);
    const int t1 = tile + S;
    if (t1 < nT) {
      e = (t1 << 6) + el;
      sv = eidx[e]; dv = eidx[NE + e];
      LOAD_ROWS(sv, dv, e);                  // in-flight for first iteration
    }
    const int t2 = tile + 2 * S;
    if (t2 < nT) { e = (t2 << 6) + el; sN = eidx[e]; dN = eidx[NE + e]; }
  }
  __syncthreads();

  int cur = 0;
  while (tile < nT) {
    const int tW = tile + S, tI = tile + 2 * S, tX = tile + 3 * S;
    if (tW < nT) WRITE_EIN(sEin[cur ^ 1]);                  // regs(t+1) -> LDS
    if (tI < nT) { const int e = (tI << 6) + el; LOAD_ROWS(sN, dN, e); }
    if (tX < nT) { const int e = (tX << 6) + el; sN = eidx[e]; dN = eidx[NE + e]; }

    // ---- layer 1: 64 edges x 32 h per wave ----
    const short* Ecur = sEin[cur];
    f32x4 acc1[2][4];
    #pragma unroll
    for (int nn = 0; nn < 2; ++nn)
      #pragma unroll
      for (int j = 0; j < 4; ++j) acc1[nn][j] = zero;
    #pragma unroll
    for (int kk = 0; kk < 6; ++kk) {
      #pragma unroll
      for (int j = 0; j < 4; ++j) {
        s16x8 ef = *(const s16x8*)&Ecur[(j*16 + r)*SEI + kk*32 + g*8];
        acc1[0][j] = __builtin_amdgcn_mfma_f32_16x16x32_bf16(w1f[0][kk], ef, acc1[0][j], 0, 0, 0);
        acc1[1][j] = __builtin_amdgcn_mfma_f32_16x16x32_bf16(w1f[1][kk], ef, acc1[1][j], 0, 0, 0);
      }
    }
    #pragma unroll
    for (int nn = 0; nn < 2; ++nn)
      #pragma unroll
      for (int j = 0; j < 4; ++j) {
        s16x4 pk;
        #pragma unroll
        for (int q = 0; q < 4; ++q) {
          float v = acc1[nn][j][q] + b1r[nn][q];
          pk[q] = f2bf(v > 0.f ? v : 0.f);
        }
        *(s16x4*)&sEh[(j*16 + r)*SEH + (wv*2+nn)*16 + g*4] = pk;
      }
    __syncthreads();                         // Eh ready

    // ---- layer 2: d-tile wv over 64 edges ----
    const int ebase = tile << 6;
    #pragma unroll
    for (int j = 0; j < 4; ++j) {
      f32x4 a2 = zero;
      #pragma unroll
      for (int kk = 0; kk < 4; ++kk) {
        s16x8 hf = *(const s16x8*)&sEh[(j*16 + r)*SEH + kk*32 + g*8];
        a2 = __builtin_amdgcn_mfma_f32_16x16x32_bf16(w2f[kk], hf, a2, 0, 0, 0);
      }
      f32x4 v = a2 + b2r;
      *(f32x4*)&edge_out[(size_t)(ebase + j*16 + r)*64 + wv*16 + g*4] = v;
    }
    __syncthreads();                         // Eh free; Ein(next) visible
    cur ^= 1;
    tile += S;
  }
}

// ---------------- aggregation (gather) ----------------
__global__ __launch_bounds__(256)
void agg_kernel(const float* __restrict__ eo, const int* __restrict__ offs,
                const int* __restrict__ elist, float* __restrict__ agg) {
  const int w = threadIdx.x >> 6;
  const int lane = threadIdx.x & 63;
  for (int i = blockIdx.x * 4 + w; i < NN; i += (int)gridDim.x * 4) {
    int j = offs[i];
    const int end = offs[i + 1];
    float acc0 = 0.f, acc1 = 0.f;
    for (; j + 8 <= end; j += 8) {
      int e0 = elist[j],   e1 = elist[j+1], e2 = elist[j+2], e3 = elist[j+3];
      int e4 = elist[j+4], e5 = elist[j+5], e6 = elist[j+6], e7 = elist[j+7];
      float v0 = eo[(size_t)e0*64 + lane];
      float v1 = eo[(size_t)e1*64 + lane];
      float v2 = eo[(size_t)e2*64 + lane];
      float v3 = eo[(size_t)e3*64 + lane];
      float v4 = eo[(size_t)e4*64 + lane];
      float v5 = eo[(size_t)e5*64 + lane];
      float v6 = eo[(size_t)e6*64 + lane];
      float v7 = eo[(size_t)e7*64 + lane];
      acc0 += (v0 + v1) + (v2 + v3);
      acc1 += (v4 + v5) + (v6 + v7);
    }
    for (; j < end; ++j) acc0 += eo[(size_t)elist[j]*64 + lane];
    agg[(size_t)i*64 + lane] = acc0 + acc1;
  }
}

// ---------------- node model ----------------
// One 64-node tile per block (grid = 313). agg aliases x_out: block reads
// rows of its own tile, overwrites exactly those rows (disjoint per block).
__global__ __launch_bounds__(256, 2)
void node_kernel(const float* __restrict__ x, const float* agg,
                 const float* __restrict__ f,
                 const float* __restrict__ Wn1, const float* __restrict__ bn1,
                 const float* __restrict__ Wn2, const float* __restrict__ bn2,
                 float* x_out)
{
  __shared__ __align__(16) short sEin1[64 * SEI];
  __shared__ __align__(16) short sEh[64 * SEH];

  const int t = threadIdx.x;
  const int wv = t >> 6, lane = t & 63;
  const int r = lane & 15, g = lane >> 4;

  s16x8 w1f[2][6], w2f[4];
  f32x4 b1r[2], b2r;
  load_wfrags(Wn1, Wn2, bn1, bn2, wv, r, g, w1f, w2f, b1r, &b2r);

  const int el = t >> 2, p = t & 3;
  const f32x4 zero = {0.f, 0.f, 0.f, 0.f};
  const int base = blockIdx.x << 6;
  const int i = base + el;

  f32x4 L[12];
  if (i < NN) {
    const f32x4* ps_ = (const f32x4*)(x   + (size_t)i*64 + p*16);
    const f32x4* pa_ = (const f32x4*)(agg + (size_t)i*64 + p*16);
    const f32x4* pf_ = (const f32x4*)(f   + (size_t)i*64 + p*16);
    L[0]=ps_[0]; L[1]=ps_[1]; L[2]=ps_[2];  L[3]=ps_[3];
    L[4]=pa_[0]; L[5]=pa_[1]; L[6]=pa_[2];  L[7]=pa_[3];
    L[8]=pf_[0]; L[9]=pf_[1]; L[10]=pf_[2]; L[11]=pf_[3];
  } else {
    #pragma unroll
    for (int q = 0; q < 12; ++q) L[q] = zero;
  }
  {
    short* stg_ = sEin1 + el*SEI + p*16;
    ((s16x8*)stg_)[0]       = cvt8(L[0], L[1]);
    ((s16x8*)stg_)[1]       = cvt8(L[2], L[3]);
    ((s16x8*)(stg_+64))[0]  = cvt8(L[4], L[5]);
    ((s16x8*)(stg_+64))[1]  = cvt8(L[6], L[7]);
    ((s16x8*)(stg_+128))[0] = cvt8(L[8], L[9]);
    ((s16x8*)(stg_+128))[1] = cvt8(L[10], L[11]);
  }
  __syncthreads();

  f32x4 acc1[2][4];
  #pragma unroll
  for (int nn = 0; nn < 2; ++nn)
    #pragma unroll
    for (int j = 0; j < 4; ++j) acc1[nn][j] = zero;
  #pragma unroll
  for (int kk = 0; kk < 6; ++kk) {
    #pragma unroll
    for (int j = 0; j < 4; ++j) {
      s16x8 ef = *(const s16x8*)&sEin1[(j*16 + r)*SEI + kk*32 + g*8];
      acc1[0][j] = __builtin_amdgcn_mfma_f32_16x16x32_bf16(w1f[0][kk], ef, acc1[0][j], 0, 0, 0);
      acc1[1][j] = __builtin_amdgcn_mfma_f32_16x16x32_bf16(w1f[1][kk], ef, acc1[1][j], 0, 0, 0);
    }
  }
  #pragma unroll
  for (int nn = 0; nn < 2; ++nn)
    #pragma unroll
    for (int j = 0; j < 4; ++j) {
      s16x4 pk;
      #pragma unroll
      for (int q = 0; q < 4; ++q) {
        float v = acc1[nn][j][q] + b1r[nn][q];
        pk[q] = f2bf(v > 0.f ? v : 0.f);
      }
      *(s16x4*)&sEh[(j*16 + r)*SEH + (wv*2+nn)*16 + g*4] = pk;
    }
  __syncthreads();

  #pragma unroll
  for (int j = 0; j < 4; ++j) {
    f32x4 a2 = zero;
    #pragma unroll
    for (int kk = 0; kk < 4; ++kk) {
      s16x8 hf = *(const s16x8*)&sEh[(j*16 + r)*SEH + kk*32 + g*8];
      a2 = __builtin_amdgcn_mfma_f32_16x16x32_bf16(w2f[kk], hf, a2, 0, 0, 0);
    }
    const int row = base + j*16 + r;
    if (row < NN) {
      f32x4 v = a2 + b2r;
      *(f32x4*)&x_out[(size_t)row*64 + wv*16 + g*4] = v;
    }
  }
}

extern "C" void kernel_launch(void* const* d_in, const int* in_sizes, int n_in,
                              void* d_out, int out_size, void* d_ws, size_t ws_size,
                              hipStream_t stream) {
  const float* x   = (const float*)d_in[0];
  const int*   ei  = (const int*)d_in[1];
  const float* ea  = (const float*)d_in[2];
  const float* f   = (const float*)d_in[3];
  const float* We1 = (const float*)d_in[4];
  const float* be1 = (const float*)d_in[5];
  const float* We2 = (const float*)d_in[6];
  const float* be2 = (const float*)d_in[7];
  const float* Wn1 = (const float*)d_in[8];
  const float* bn1 = (const float*)d_in[9];
  const float* Wn2 = (const float*)d_in[10];
  const float* bn2 = (const float*)d_in[11];

  float* x_out    = (float*)d_out;                    // [20000*64] — doubles as agg
  float* edge_out = x_out + (size_t)NN * 64;          // [640000*64]

  // CSR scratch in d_ws: cursor[NN] | offs[NN+1] | elist[NE]  (~2.8 MB)
  int* cursor = (int*)d_ws;
  int* offs   = cursor + NN;
  int* elist  = offs + NN + 8;

  hipMemsetAsync(cursor, 0, NN * sizeof(int), stream);
  count_kernel<<<1024, 256, 0, stream>>>(ei, cursor);
  scan_kernel<<<1, 1024, 0, stream>>>(cursor, offs);
  scatter_kernel<<<1024, 256, 0, stream>>>(ei, cursor, elist);
  edge_kernel<<<512, 256, 0, stream>>>(x, ei, ea, We1, be1, We2, be2, edge_out);
  agg_kernel<<<1024, 256, 0, stream>>>(edge_out, offs, elist, x_out);
  node_kernel<<<313, 256, 0, stream>>>(x, x_out, f, Wn1, bn1, Wn2, bn2, x_out);
}